// Round 2
// baseline (711.524 us; speedup 1.0000x reference)
//
#include <hip/hip_runtime.h>

using half_t = _Float16;
using half8  = __attribute__((ext_vector_type(8))) _Float16;
using half4  = __attribute__((ext_vector_type(4))) _Float16;
using f32x4  = __attribute__((ext_vector_type(4))) float;

#define MFMA(a, b, c) __builtin_amdgcn_mfma_f32_16x16x32_f16((a), (b), (c), 0, 0, 0)

// async global->LDS, 16 B per lane. LDS dest = wave-uniform base + lane*16.
#define GLL16(g, l)                                                     \
  __builtin_amdgcn_global_load_lds(                                     \
      (__attribute__((address_space(1))) void*)(g),                     \
      (__attribute__((address_space(3))) void*)(l), 16, 0, 0)

__device__ __forceinline__ half8 ld8(const half_t* p) { return *(const half8*)p; }

// qk scale folded into qh epilogue: 0.125 * log2(e) so softmax uses exp2 directly
#define QSCALE 0.18033688011112042f
#define LOG2E  1.4426950408889634f

// ---------------------------------------------------------------- convert
__global__ void cvt_f32_f16(const float* __restrict__ src, half_t* __restrict__ dst, int n4) {
  int i = blockIdx.x * blockDim.x + threadIdx.x;
  if (i < n4) {
    f32x4 v = ((const f32x4*)src)[i];
    half4 h;
    h[0] = (half_t)v[0]; h[1] = (half_t)v[1]; h[2] = (half_t)v[2]; h[3] = (half_t)v[3];
    ((half4*)dst)[i] = h;
  }
}

// ---------------------------------------------------------------- GEMM (C = A * Bt^T), m97 structure
// EPI 0: qh  -> (B,H,Lq,D) f16, scaled by QSCALE   (M=4096, N=1024)
// EPI 1: kv  -> k (B,H,Lkv,D), vT (B,H,D,Lkv) f16  (M=8192, N=2048)
// EPI 2: out -> fp32 + bias                        (M=4096, N=1024)
template <int EPI>
__global__ __launch_bounds__(256) void gemm_kernel(
    const half_t* __restrict__ A, const half_t* __restrict__ Bt,
    int M, int N, int K,
    half_t* __restrict__ oh, half_t* __restrict__ ov,
    float* __restrict__ of, const float* __restrict__ bias) {
  __shared__ alignas(16) half_t sA[128 * 32];
  __shared__ alignas(16) half_t sB[128 * 32];
  const int tid  = threadIdx.x;
  const int lane = tid & 63;
  const int w    = tid >> 6;
  const int c    = lane & 15;
  const int quad = lane >> 4;
  const int m0 = blockIdx.y * 128;
  const int n0 = blockIdx.x * 128;
  const int wm = (w & 1) * 64;
  const int wn = (w >> 1) * 64;

  f32x4 acc[4][4] = {};

  const int srow = tid >> 2;
  const int scol = (tid & 3) * 8;
  const half_t* Ag = A + (size_t)(m0 + srow) * K + scol;
  const half_t* Bg = Bt + (size_t)(n0 + srow) * K + scol;

  for (int k0 = 0; k0 < K; k0 += 32) {
    GLL16(Ag + k0,            sA + tid * 8);
    GLL16(Ag + k0 + 64 * K,   sA + tid * 8 + 2048);
    GLL16(Bg + k0,            sB + tid * 8);
    GLL16(Bg + k0 + 64 * K,   sB + tid * 8 + 2048);
    __syncthreads();
    half8 a[4], b[4];
#pragma unroll
    for (int i = 0; i < 4; ++i) a[i] = ld8(&sA[(wm + i * 16 + c) * 32 + quad * 8]);
#pragma unroll
    for (int j = 0; j < 4; ++j) b[j] = ld8(&sB[(wn + j * 16 + c) * 32 + quad * 8]);
#pragma unroll
    for (int i = 0; i < 4; ++i)
#pragma unroll
      for (int j = 0; j < 4; ++j) acc[i][j] = MFMA(a[i], b[j], acc[i][j]);
    __syncthreads();
  }

#pragma unroll
  for (int i = 0; i < 4; ++i) {
    const int mbase = m0 + wm + i * 16 + quad * 4;
#pragma unroll
    for (int j = 0; j < 4; ++j) {
      const int n = n0 + wn + j * 16 + c;
      if (EPI == 0) {
        const int bb = mbase >> 10, qi = mbase & 1023;
        const int hh = n >> 6, d = n & 63;
        half_t* p = oh + (((size_t)(bb * 16 + hh) * 1024 + qi) * 64 + d);
#pragma unroll
        for (int r = 0; r < 4; ++r) p[(size_t)r * 64] = (half_t)(acc[i][j][r] * QSCALE);
      } else if (EPI == 1) {
        const int bb = mbase >> 11, kvi = mbase & 2047;
        if (n < 1024) {
          const int hh = n >> 6, d = n & 63;
          half_t* p = oh + (((size_t)(bb * 16 + hh) * 2048 + kvi) * 64 + d);
#pragma unroll
          for (int r = 0; r < 4; ++r) p[(size_t)r * 64] = (half_t)acc[i][j][r];
        } else {
          const int nn = n - 1024;
          const int hh = nn >> 6, d = nn & 63;
          half4 hv;
#pragma unroll
          for (int r = 0; r < 4; ++r) hv[r] = (half_t)acc[i][j][r];
          *(half4*)&ov[((size_t)(bb * 16 + hh) * 64 + d) * 2048 + kvi] = hv;
        }
      } else {
        const float bv = bias[n];
#pragma unroll
        for (int r = 0; r < 4; ++r) of[(size_t)(mbase + r) * N + n] = acc[i][j][r] + bv;
      }
    }
  }
}

// ---------------------------------------------------------------- flash attention, barrier-free
// grid: ((b*16+h)*16 + qtile), 256 threads (4 waves), 64 q-rows/block, 16 q-rows/wave.
// All Q/K/V fragments load straight from global (coalesced 16B/lane, L1/L2-resident);
// only the P C-layout -> A-layout transpose goes through (per-wave) LDS — no barriers.
__global__ __launch_bounds__(256) void attn_kernel(
    const half_t* __restrict__ qh, const half_t* __restrict__ kk,
    const half_t* __restrict__ vt, const float* __restrict__ pos,
    half_t* __restrict__ xout) {
  __shared__ alignas(16) half_t Ps[4 * 16 * 72];
  const int tid  = threadIdx.x;
  const int lane = tid & 63;
  const int w    = tid >> 6;
  const int c    = lane & 15;
  const int quad = lane >> 4;
  const int bh = blockIdx.x >> 4;
  const int q0 = (blockIdx.x & 15) << 6;
  const int b  = bh >> 4;
  const int h  = bh & 15;

  const half_t* qg = qh + (((size_t)bh << 10) + q0) * 64;
  const half_t* kg = kk + ((size_t)bh * 2048) * 64;
  const half_t* vg = vt + ((size_t)bh * 64) * 2048;
  const float*  pg = pos + (((size_t)bh << 10) + q0 + w * 16 + quad * 4) * 1024 + c;
  half_t* Pw = Ps + w * 16 * 72;

  // Q fragments: loop-invariant, straight from global
  const half8 aq0 = ld8(&qg[(size_t)(w * 16 + c) * 64 + quad * 8]);
  const half8 aq1 = ld8(&qg[(size_t)(w * 16 + c) * 64 + 32 + quad * 8]);

  f32x4 o[4] = {};
  float l_run[4] = {0.f, 0.f, 0.f, 0.f};

#pragma unroll 1
  for (int kv0 = 0; kv0 < 2048; kv0 += 64) {
    const bool haspos = (kv0 < 1024);
    // prefetch pos (nontemporal stream) — overlaps the QK MFMAs
    float posv[4][4];
    if (haspos) {
#pragma unroll
      for (int r = 0; r < 4; ++r)
#pragma unroll
        for (int t = 0; t < 4; ++t)
          posv[t][r] = __builtin_nontemporal_load(&pg[(size_t)r * 1024 + kv0 + t * 16]);
    }

    // S = Q K^T : B-frags direct from global K rows
    f32x4 s[4];
#pragma unroll
    for (int t = 0; t < 4; ++t) {
      const half_t* kr = &kg[(size_t)(kv0 + t * 16 + c) * 64 + quad * 8];
      f32x4 z = {};
      z = MFMA(aq0, ld8(kr), z);
      z = MFMA(aq1, ld8(kr + 32), z);
      s[t] = z;
    }

    // p = exp2(s + pos*log2e)  (scale pre-folded into qh); accumulate l per-lane
#pragma unroll
    for (int t = 0; t < 4; ++t)
#pragma unroll
      for (int r = 0; r < 4; ++r) {
        const float lg = haspos ? __builtin_fmaf(posv[t][r], LOG2E, s[t][r]) : s[t][r];
        const float p  = exp2f(lg);
        l_run[r] += p;
        Pw[(quad * 4 + r) * 72 + t * 16 + c] = (half_t)p;
      }

    // O += P V : P via per-wave LDS round trip (no barrier), V-frags direct from vT
#pragma unroll
    for (int hk = 0; hk < 2; ++hk) {
      const half8 ap = ld8(&Pw[c * 72 + hk * 32 + quad * 8]);
#pragma unroll
      for (int jd = 0; jd < 4; ++jd) {
        const half8 bv = ld8(&vg[(size_t)(jd * 16 + c) * 2048 + kv0 + hk * 32 + quad * 8]);
        o[jd] = MFMA(ap, bv, o[jd]);
      }
    }
  }

  // reduce l across the 16 lanes of each quad-row group (pure sum — no max path)
#pragma unroll
  for (int r = 0; r < 4; ++r) {
    float l = l_run[r];
    l += __shfl_xor(l, 1, 16);
    l += __shfl_xor(l, 2, 16);
    l += __shfl_xor(l, 4, 16);
    l += __shfl_xor(l, 8, 16);
    l_run[r] = 1.0f / l;
  }

#pragma unroll
  for (int jd = 0; jd < 4; ++jd)
#pragma unroll
    for (int r = 0; r < 4; ++r) {
      const int qrow = q0 + w * 16 + quad * 4 + r;
      const int d    = jd * 16 + c;
      xout[((size_t)b * 1024 + qrow) * 1024 + h * 64 + d] = (half_t)(o[jd][r] * l_run[r]);
    }
}

// ---------------------------------------------------------------- launch
extern "C" void kernel_launch(void* const* d_in, const int* in_sizes, int n_in,
                              void* d_out, int out_size, void* d_ws, size_t ws_size,
                              hipStream_t stream) {
  const float* q   = (const float*)d_in[0];
  const float* kv  = (const float*)d_in[1];
  const float* pos = (const float*)d_in[2];
  const float* qw  = (const float*)d_in[3];
  const float* kvw = (const float*)d_in[4];
  const float* pw  = (const float*)d_in[5];
  const float* pb  = (const float*)d_in[6];
  float* out = (float*)d_out;

  char* ws = (char*)d_ws;
  half_t* qf   = (half_t*)(ws);
  half_t* kvf  = (half_t*)(ws + (size_t)(8)  * 1048576);
  half_t* qwf  = (half_t*)(ws + (size_t)(24) * 1048576);
  half_t* kvwf = (half_t*)(ws + (size_t)(26) * 1048576);
  half_t* pwf  = (half_t*)(ws + (size_t)(30) * 1048576);
  half_t* qh   = (half_t*)(ws + (size_t)(32) * 1048576);
  half_t* kk   = (half_t*)(ws + (size_t)(40) * 1048576);
  half_t* vt   = (half_t*)(ws + (size_t)(56) * 1048576);
  half_t* xb   = (half_t*)(ws + (size_t)(72) * 1048576);

  auto cvt = [&](const float* s, half_t* d, int n) {
    cvt_f32_f16<<<n / 1024, 256, 0, stream>>>(s, d, n / 4);
  };
  cvt(q,   qf,   4 * 1024 * 1024);
  cvt(kv,  kvf,  4 * 2048 * 1024);
  cvt(qw,  qwf,  1024 * 1024);
  cvt(kvw, kvwf, 2048 * 1024);
  cvt(pw,  pwf,  1024 * 1024);

  gemm_kernel<0><<<dim3(1024 / 128, 4096 / 128), 256, 0, stream>>>(
      qf, qwf, 4096, 1024, 1024, qh, nullptr, nullptr, nullptr);
  gemm_kernel<1><<<dim3(2048 / 128, 8192 / 128), 256, 0, stream>>>(
      kvf, kvwf, 8192, 2048, 1024, kk, vt, nullptr, nullptr);
  attn_kernel<<<4 * 16 * 16, 256, 0, stream>>>(qh, kk, vt, pos, xb);
  gemm_kernel<2><<<dim3(1024 / 128, 4096 / 128), 256, 0, stream>>>(
      xb, pwf, 4096, 1024, 1024, nullptr, nullptr, out, pb);
}